// Round 6
// baseline (165.497 us; speedup 1.0000x reference)
//
#include <hip/hip_runtime.h>

#define NUM_LAYERS 1000
#define DIM 10
#define STRIDE 112           // floats per affine slot (10x11 = 110, padded to 112)
#define LPB 16               // layers per block in K1
#define NBLK 63              // ceil(1000/16)
#define WQ4 320              // float4 per wave-tile (64 lanes * 5)
#define TILE_Q4 1280         // float4 per block-tile (4 waves)
#define APPLY_GRID 1303      // ~5.1 blocks/CU, all resident; 3907 tiles / 1303 = 3 iters

// Affine stored col-major in a slot: slot[j*10 + r] = M[r][j] for j<10,
// slot[100 + r] = c[r]. Compose dst = g(f(.)): col_j(dst) = M_g * col_j(f)
// (+ c_g when j==10). Lane j (0..10) owns column j.
__device__ inline void compose_one(const float* __restrict__ src,
                                   float* __restrict__ dst,
                                   int c, int lane) {
    const float* F = src + (size_t)(2 * c) * STRIDE;
    const float* G = src + (size_t)(2 * c + 1) * STRIDE;
    float colf[DIM], o[DIM];
    #pragma unroll
    for (int r = 0; r < DIM; ++r) colf[r] = F[lane * DIM + r];
    #pragma unroll
    for (int r = 0; r < DIM; ++r) {
        float acc = (lane == DIM) ? G[100 + r] : 0.f;
        #pragma unroll
        for (int k = 0; k < DIM; ++k)
            acc += G[k * DIM + r] * colf[k];
        o[r] = acc;
    }
    float* D = dst + (size_t)c * STRIDE;
    #pragma unroll
    for (int r = 0; r < DIM; ++r) D[lane * DIM + r] = o[r];
}

// ---------------------------------------------------------------------------
// K1 (proven round-0): block b composes layers [b*16, b*16+16) via a 4-level
// LDS tree: 16 -> 8 -> 4 -> 2 -> 1. One wave per compose.
// ---------------------------------------------------------------------------
__global__ __launch_bounds__(1024) void compose16(const float* __restrict__ Ws,
                                                  const float* __restrict__ bs,
                                                  float* __restrict__ wsout) {
    __shared__ float A[LPB * STRIDE];
    __shared__ float B[(LPB / 2) * STRIDE];
    const int tid = threadIdx.x;
    const int blk = blockIdx.x;

    for (int e = tid; e < LPB * 100; e += 1024) {
        int ll = e / 100, rem = e % 100;      // rem = r*10 + k
        int r = rem / 10, k = rem % 10;
        int l = blk * LPB + ll;
        float v = (l < NUM_LAYERS) ? Ws[(size_t)l * 100 + rem]
                                   : (r == k ? 1.f : 0.f);
        A[ll * STRIDE + k * DIM + r] = v;
    }
    for (int e = tid; e < LPB * DIM; e += 1024) {
        int ll = e / DIM, r = e % DIM;
        int l = blk * LPB + ll;
        float v = (l < NUM_LAYERS) ? bs[(size_t)l * DIM + r] : 0.f;
        A[ll * STRIDE + 100 + r] = v;
    }

    const int wave = tid >> 6, lane = tid & 63;
    const float* src = A;
    float* dst = B;
    for (int n = LPB / 2; n >= 1; n >>= 1) {   // n = 8,4,2,1
        __syncthreads();
        if (wave < n && lane <= DIM) compose_one(src, dst, wave, lane);
        const float* t = dst; dst = (float*)src; src = t;
    }
    __syncthreads();
    if (tid < 110) wsout[(size_t)blk * STRIDE + tid] = A[tid];
}

// ---------------------------------------------------------------------------
// K2 (proven round-0): one block folds the 63 chunk affines (padded to 64)
// via a 6-level tree. Writes the final affine ROW-major:
// aff[r*10+k] = M[r][k], aff[100+r] = c[r].
// ---------------------------------------------------------------------------
__global__ __launch_bounds__(1024) void compose_tree64(const float* __restrict__ wsin,
                                                       float* __restrict__ aff) {
    __shared__ float A[64 * STRIDE];
    __shared__ float B[32 * STRIDE];
    const int tid = threadIdx.x;

    for (int e = tid; e < 64 * STRIDE; e += 1024) {
        int chunk = e / STRIDE, pos = e % STRIDE;
        float v;
        if (pos >= 110)        v = 0.f;
        else if (chunk < NBLK) v = wsin[(size_t)chunk * STRIDE + pos];
        else v = (pos < 100 && (pos / 10 == pos % 10)) ? 1.f : 0.f;  // identity
        A[e] = v;
    }

    const int wave = tid >> 6, lane = tid & 63;
    const float* src = A;
    float* dst = B;
    for (int n = 32; n >= 1; n >>= 1) {        // n = 32,16,8,4,2,1
        __syncthreads();
        if (lane <= DIM)
            for (int c = wave; c < n; c += 16)
                compose_one(src, dst, c, lane);
        const float* t = dst; dst = (float*)src; src = t;
    }
    __syncthreads();
    if (tid < 110) {
        if (tid < 100) {
            int j = tid / DIM, r = tid % DIM;  // A[j*10+r] = M[r][j]
            aff[r * DIM + j] = A[tid];
        } else {
            aff[tid] = A[tid];                 // bias
        }
    }
}

// ---------------------------------------------------------------------------
// K3: out = M x + c. PERSISTENT grid-stride + per-wave software pipeline.
// No __syncthreads anywhere; intra-wave LDS redistribution ordered by inline
// lgkmcnt(0) + sched_barrier(0) (rule #18). Next tile's global loads are
// issued between the LDS read and the compute of the current tile, so iter-k
// stores and iter-(k+1) loads overlap in flight (compiler emits counted
// vmcnt waits). Loads use clamped indices (block-uniform branch only);
// stores are lane-predicated. LDS read stride 80 B covers all 32 banks per
// 8 lanes -> conflict-free (measured 0 in round 5).
// ---------------------------------------------------------------------------
__global__ __launch_bounds__(256) void apply_affine(const float* __restrict__ x,
                                                    const float* __restrict__ aff,
                                                    float* __restrict__ out,
                                                    int nq4, int ntiles) {
    __shared__ float4 lds4[4][WQ4];
    __shared__ float4 s4[28];                  // 112 floats (110 used)
    const int tid  = threadIdx.x;
    const int w    = tid >> 6, lane = tid & 63;
    const float* __restrict__ s = (const float*)s4;

    // Each wave redundantly stages the affine (identical values -> no tearing;
    // each wave's own lgkm fence below covers its copy).
    if (lane < 28) s4[lane] = ((const float4*)aff)[lane];

    const float4* __restrict__ xin = (const float4*)x;
    float4* __restrict__ op = (float4*)out;
    const int qmax = nq4 - 1;

    int t = blockIdx.x;
    if (t >= ntiles) return;
    int base = t * TILE_Q4 + w * WQ4 + lane;   // this wave-lane's first float4

    // prolog: load tile t (clamped addresses; OOB lanes compute garbage,
    // stores are predicated)
    float4 r0, r1, r2, r3, r4;
    {
        int q;
        q = base + 0 * 64; q = q < qmax ? q : qmax; r0 = xin[q];
        q = base + 1 * 64; q = q < qmax ? q : qmax; r1 = xin[q];
        q = base + 2 * 64; q = q < qmax ? q : qmax; r2 = xin[q];
        q = base + 3 * 64; q = q < qmax ? q : qmax; r3 = xin[q];
        q = base + 4 * 64; q = q < qmax ? q : qmax; r4 = xin[q];
    }

    for (;;) {
        // stage current tile regs -> this wave's private LDS region
        lds4[w][0 * 64 + lane] = r0;
        lds4[w][1 * 64 + lane] = r1;
        lds4[w][2 * 64 + lane] = r2;
        lds4[w][3 * 64 + lane] = r3;
        lds4[w][4 * 64 + lane] = r4;

        asm volatile("s_waitcnt lgkmcnt(0)" ::: "memory");
        __builtin_amdgcn_sched_barrier(0);

        // cross-lane read: thread owns 20 contiguous floats = rows {2T, 2T+1}
        float xv[20];
        #pragma unroll
        for (int i = 0; i < 5; ++i) {
            float4 v = lds4[w][5 * lane + i];
            xv[4*i+0] = v.x; xv[4*i+1] = v.y; xv[4*i+2] = v.z; xv[4*i+3] = v.w;
        }

        // issue NEXT tile's loads now (overlaps compute + stores below)
        const int tn = t + gridDim.x;
        const bool more = tn < ntiles;         // block-uniform
        const int nbase = tn * TILE_Q4 + w * WQ4 + lane;
        if (more) {
            int q;
            q = nbase + 0 * 64; q = q < qmax ? q : qmax; r0 = xin[q];
            q = nbase + 1 * 64; q = q < qmax ? q : qmax; r1 = xin[q];
            q = nbase + 2 * 64; q = q < qmax ? q : qmax; r2 = xin[q];
            q = nbase + 3 * 64; q = q < qmax ? q : qmax; r3 = xin[q];
            q = nbase + 4 * 64; q = q < qmax ? q : qmax; r4 = xin[q];
        }

        float o[20];
        #pragma unroll
        for (int rr = 0; rr < 2; ++rr)
            #pragma unroll
            for (int j = 0; j < DIM; ++j) {
                float acc = s[100 + j];
                #pragma unroll
                for (int k = 0; k < DIM; ++k)
                    acc += s[j * DIM + k] * xv[rr * DIM + k];
                o[rr * DIM + j] = acc;
            }

        // write results to the SAME per-lane addresses (in-order LDS per wave:
        // these writes cannot pass the xv reads above)
        #pragma unroll
        for (int i = 0; i < 5; ++i)
            lds4[w][5 * lane + i] = make_float4(o[4*i+0], o[4*i+1], o[4*i+2], o[4*i+3]);

        asm volatile("s_waitcnt lgkmcnt(0)" ::: "memory");
        __builtin_amdgcn_sched_barrier(0);

        // coalesced, lane-predicated stores
        {
            float4 t0 = lds4[w][0 * 64 + lane];
            float4 t1 = lds4[w][1 * 64 + lane];
            float4 t2 = lds4[w][2 * 64 + lane];
            float4 t3 = lds4[w][3 * 64 + lane];
            float4 t4 = lds4[w][4 * 64 + lane];
            int q;
            q = base + 0 * 64; if (q < nq4) op[q] = t0;
            q = base + 1 * 64; if (q < nq4) op[q] = t1;
            q = base + 2 * 64; if (q < nq4) op[q] = t2;
            q = base + 3 * 64; if (q < nq4) op[q] = t3;
            q = base + 4 * 64; if (q < nq4) op[q] = t4;
        }

        if (!more) break;
        t = tn;
        base = nbase;
    }
}

extern "C" void kernel_launch(void* const* d_in, const int* in_sizes, int n_in,
                              void* d_out, int out_size, void* d_ws, size_t ws_size,
                              hipStream_t stream) {
    const float* x  = (const float*)d_in[0];   // [BATCH, 10]
    const float* Ws = (const float*)d_in[1];   // [1000, 10, 10]
    const float* bs = (const float*)d_in[2];   // [1000, 10]
    float* out = (float*)d_out;

    float* ws_chunks = (float*)d_ws;                      // NBLK * STRIDE floats
    float* ws_aff    = ws_chunks + NBLK * STRIDE;         // 112 floats (16B aligned)

    compose16<<<NBLK, 1024, 0, stream>>>(Ws, bs, ws_chunks);
    compose_tree64<<<1, 1024, 0, stream>>>(ws_chunks, ws_aff);

    const int nq4 = in_sizes[0] / 4;                      // in_sizes is in floats
    const int ntiles = (nq4 + TILE_Q4 - 1) / TILE_Q4;
    const int blocks = (ntiles < APPLY_GRID) ? ntiles : APPLY_GRID;
    apply_affine<<<blocks, 256, 0, stream>>>(x, ws_aff, out, nq4, ntiles);
}